// Round 16
// baseline (200.854 us; speedup 1.0000x reference)
//
#include <hip/hip_runtime.h>
#include <hip/hip_bf16.h>

#define HID 128
#define DMAX 64
#define ESHARD 2048

typedef unsigned int uint;
typedef unsigned short ushort;
using short8 = __attribute__((ext_vector_type(8))) short;
using f32x4  = __attribute__((ext_vector_type(4))) float;

#define MFMA_B16(a, b, c) __builtin_amdgcn_mfma_f32_16x16x32_bf16(a, b, c, 0, 0, 0)

__device__ inline ushort bf16rn(float f) {
  uint u = __float_as_uint(f);
  u += 0x7fff + ((u >> 16) & 1);
  return (ushort)(u >> 16);
}
__device__ inline uint packbf(float a, float b) {
  return (uint)bf16rn(a) | ((uint)bf16rn(b) << 16);
}
__device__ inline float bflo(uint u) { return __uint_as_float(u << 16); }
__device__ inline float bfhi(uint u) { return __uint_as_float(u & 0xffff0000u); }

// ---------------- fused prep: deg zero + g zero + mv zero + xp pack + weight cast ----------------
__global__ __launch_bounds__(256) void k_prep(
    const float* __restrict__ x, const float* __restrict__ pos,
    const float* __restrict__ c1w2, const float* __restrict__ c2w1, const float* __restrict__ c2w2,
    float4* __restrict__ xp, int* __restrict__ deg, float* __restrict__ g,
    float* __restrict__ mv,
    ushort* __restrict__ w1t, ushort* __restrict__ wdt,
    ushort* __restrict__ wst, ushort* __restrict__ w2t,
    int N, int G, int Npad) {
  int idx = blockIdx.x * 256 + threadIdx.x;
  if (idx < Npad) deg[idx] = 0;
  if (idx < G * HID) g[idx] = 0.f;
  if (idx < 256) mv[idx] = 0.f;
  if (idx < N) {
    xp[idx] = make_float4(pos[3 * idx], pos[3 * idx + 1], pos[3 * idx + 2], x[idx]);
  }
  // weight cast+transpose: 4 matrices x 16384 (grid is exactly 65536 threads)
  {
    int m = idx >> 14, e = idx & 16383;
    int c = e >> 7, k = e & 127;
    const float* src;
    ushort* dst;
    if (m == 0)      { src = c1w2;              dst = w1t; }
    else if (m == 1) { src = c2w1;              dst = wdt; }
    else if (m == 2) { src = c2w1 + 128 * 128;  dst = wst; }
    else             { src = c2w2;              dst = w2t; }
    dst[e] = bf16rn(src[k * 128 + c]);
  }
}

// ---------------- XCD-sharded padded-CSR build ----------------
__global__ __launch_bounds__(256) void k_build(const int* __restrict__ dstv,
                                               const int* __restrict__ srcv,
                                               int* __restrict__ deg, int* __restrict__ srcsP,
                                               int E) {
  int shard = blockIdx.x & 7;
  int base = (blockIdx.x >> 3) * ESHARD;
  int lim = min(base + ESHARD, E);
  for (int e = base + threadIdx.x; e < lim; e += 256) {
    int d = dstv[e];
    if (((d >> 5) & 7) == shard) {
      int s = srcv[e];
      int r = atomicAdd(&deg[d], 1);
      if (r < DMAX) srcsP[(size_t)d * DMAX + r] = s;
    }
  }
}

// ---------------- k_front: conv1 edge phase + 3-stage MFMA (h1 -> ps,pd), all LDS-resident ----------------
// 512 threads = 8 waves; 64 nodes/block. Phase A: wave wv computes conv1 h-sums for nodes
// wv*8..wv*8+7 into hl (bf16-packed, hs1 layout). Then: frag-read -> h1 -> frag-read -> ps/pd.
__global__ __launch_bounds__(512) void k_front(
    const float4* __restrict__ xp,
    const int* __restrict__ deg, const int* __restrict__ srcsP,
    const float* __restrict__ w1, const float* __restrict__ b1v,
    const ushort* __restrict__ W1t, const ushort* __restrict__ Wdt, const ushort* __restrict__ Wst,
    const float* __restrict__ b1, const float* __restrict__ bd,
    uint* __restrict__ psb, uint* __restrict__ pdb, int M) {
  __shared__ uint hl[64][68];        // hsum -> h1 -> ps tile
  __shared__ uint hd[64][68];        // pd tile
  __shared__ float sxsw[8][64];      // per-wave conv1 staging
  __shared__ float sdpw[8][3][64];
  int t = threadIdx.x;
  int l = t & 63;
  int rl = l & 15, kg = l >> 4;
  int wv = t >> 6;        // 0..7
  int rg = wv & 3;        // row group
  int cg = wv >> 2;       // col group (0..1)
  int rloc = rg * 16 + rl;
  int r = blockIdx.x * 64 + rloc;
  bool valid = (r < M);
  float dg = valid ? (float)deg[r] : 0.f;

  // ---- phase A: conv1 for 8 nodes per wave ----
  int f0 = 2 * l;
  float2 a1 = *(const float2*)&w1[HID + f0];
  float2 a2 = *(const float2*)&w1[2 * HID + f0];
  float2 a3 = *(const float2*)&w1[3 * HID + f0];
  float2 a4 = *(const float2*)&w1[4 * HID + f0];
  float w10 = w1[f0], w11 = w1[f0 + 1];
  float b10 = b1v[f0], b11 = b1v[f0 + 1];
  #pragma unroll
  for (int q = 0; q < 8; ++q) {
    int nloc = wv * 8 + q;
    int n = blockIdx.x * 64 + nloc;
    int nc = min(n, M - 1);
    int cnt = (n < M) ? min(deg[n], DMAX) : 0;
    float4 me = xp[nc];
    if (l < cnt) {
      int s = srcsP[(size_t)n * DMAX + l];
      float4 v = xp[s];
      sxsw[wv][l] = v.w;
      sdpw[wv][0][l] = v.x - me.x;
      sdpw[wv][1][l] = v.y - me.y;
      sdpw[wv][2][l] = v.z - me.z;
    }
    __syncthreads();   // uniform trip count across all waves
    float c_0 = fmaf(me.w, w10, b10);
    float c_1 = fmaf(me.w, w11, b11);
    float acc0 = 0.f, acc1 = 0.f;
    for (int k = 0; k < cnt; ++k) {
      float xj = sxsw[wv][k], d0 = sdpw[wv][0][k], d1 = sdpw[wv][1][k], d2 = sdpw[wv][2][k];
      float h0 = fmaf(xj, a1.x, fmaf(d0, a2.x, fmaf(d1, a3.x, fmaf(d2, a4.x, c_0))));
      float h1 = fmaf(xj, a1.y, fmaf(d0, a2.y, fmaf(d1, a3.y, fmaf(d2, a4.y, c_1))));
      acc0 += fmaxf(h0, 0.f);
      acc1 += fmaxf(h1, 0.f);
    }
    hl[nloc][l] = packbf(acc0, acc1);
    __syncthreads();
  }

  // ---- read own-row hsum fragments ----
  short8 af[4];
  {
    const uint* hrow = hl[rloc];
    #pragma unroll
    for (int i = 0; i < 4; ++i) af[i] = *(const short8*)&hrow[i * 16 + kg * 4];
  }
  __syncthreads();
  // ---- stage 1: h1 = relu(hsum@W1 + dg*b1) into hl (this wave's col-half) ----
  #pragma unroll
  for (int ntl = 0; ntl < 4; ++ntl) {
    int nt = cg * 4 + ntl;
    const short8* wrow = (const short8*)(W1t + (size_t)(nt * 16 + rl) * 128);
    f32x4 acc = {0.f, 0.f, 0.f, 0.f};
    acc = MFMA_B16(wrow[kg],      af[0], acc);
    acc = MFMA_B16(wrow[4 + kg],  af[1], acc);
    acc = MFMA_B16(wrow[8 + kg],  af[2], acc);
    acc = MFMA_B16(wrow[12 + kg], af[3], acc);
    int c0 = nt * 16 + kg * 4;
    f32x4 b4 = *(const f32x4*)&b1[c0];
    float v0 = fmaxf(fmaf(dg, b4[0], acc[0]), 0.f);
    float v1 = fmaxf(fmaf(dg, b4[1], acc[1]), 0.f);
    float v2 = fmaxf(fmaf(dg, b4[2], acc[2]), 0.f);
    float v3 = fmaxf(fmaf(dg, b4[3], acc[3]), 0.f);
    hl[rloc][(c0 >> 1)]     = packbf(v0, v1);
    hl[rloc][(c0 >> 1) + 1] = packbf(v2, v3);
  }
  __syncthreads();
  // ---- read own-row h1 fragments ----
  short8 bfrag[4];
  {
    const uint* hrow = hl[rloc];
    #pragma unroll
    for (int i = 0; i < 4; ++i) bfrag[i] = *(const short8*)&hrow[i * 16 + kg * 4];
  }
  __syncthreads();
  // ---- stage 2: ps into hl, pd into hd ----
  #pragma unroll
  for (int ntl = 0; ntl < 4; ++ntl) {
    int nt = cg * 4 + ntl;
    const short8* wsrow = (const short8*)(Wst + (size_t)(nt * 16 + rl) * 128);
    const short8* wdrow = (const short8*)(Wdt + (size_t)(nt * 16 + rl) * 128);
    f32x4 accS = {0.f, 0.f, 0.f, 0.f};
    f32x4 accD = {0.f, 0.f, 0.f, 0.f};
    accS = MFMA_B16(wsrow[kg],      bfrag[0], accS);
    accS = MFMA_B16(wsrow[4 + kg],  bfrag[1], accS);
    accS = MFMA_B16(wsrow[8 + kg],  bfrag[2], accS);
    accS = MFMA_B16(wsrow[12 + kg], bfrag[3], accS);
    accD = MFMA_B16(wdrow[kg],      bfrag[0], accD);
    accD = MFMA_B16(wdrow[4 + kg],  bfrag[1], accD);
    accD = MFMA_B16(wdrow[8 + kg],  bfrag[2], accD);
    accD = MFMA_B16(wdrow[12 + kg], bfrag[3], accD);
    int c0 = nt * 16 + kg * 4;
    f32x4 b4 = *(const f32x4*)&bd[c0];
    hl[rloc][(c0 >> 1)]     = packbf(accS[0], accS[1]);
    hl[rloc][(c0 >> 1) + 1] = packbf(accS[2], accS[3]);
    hd[rloc][(c0 >> 1)]     = packbf(accD[0] + b4[0], accD[1] + b4[1]);
    hd[rloc][(c0 >> 1) + 1] = packbf(accD[2] + b4[2], accD[3] + b4[3]);
  }
  __syncthreads();
  // ---- coalesced copy-out ----
  int rbase = blockIdx.x * 64;
  #pragma unroll
  for (int idx = t; idx < 64 * 16; idx += 512) {
    int row = idx >> 4, c4 = (idx & 15) * 4;
    int gr = rbase + row;
    if (gr < M) {
      *(uint4*)&psb[(size_t)gr * 64 + c4] = *(const uint4*)&hl[row][c4];
      *(uint4*)&pdb[(size_t)gr * 64 + c4] = *(const uint4*)&hd[row][c4];
    }
  }
}

// ---------------- conv2 edge phase: dwordx4 ps gather, 16 edges in flight ----------------
__global__ __launch_bounds__(64) void k_conv2(
    const float4* __restrict__ xp,
    const int* __restrict__ deg, const int* __restrict__ srcsP,
    const uint* __restrict__ pdb, const uint* __restrict__ ps,
    const float* __restrict__ wc, uint* __restrict__ hs) {
  int n = blockIdx.x;
  int lane = threadIdx.x;
  int eg = lane >> 4;
  int fb = lane & 15;
  int f0 = 8 * fb;
  __shared__ int ssrc[64];
  __shared__ float sdp[3][64];
  int cnt = min(deg[n], DMAX);
  float4 me = xp[n];
  float c0[8], c1[8], c2[8], pdv[8], acc[8];
  uint4 pdu = *(const uint4*)&pdb[(size_t)n * 64 + fb * 4];
  uint pdua[4] = {pdu.x, pdu.y, pdu.z, pdu.w};
  #pragma unroll
  for (int i = 0; i < 4; ++i) {
    pdv[2 * i]     = bflo(pdua[i]);
    pdv[2 * i + 1] = bfhi(pdua[i]);
  }
  #pragma unroll
  for (int i = 0; i < 8; ++i) {
    c0[i]  = wc[f0 + i];
    c1[i]  = wc[HID + f0 + i];
    c2[i]  = wc[2 * HID + f0 + i];
    acc[i] = 0.f;
  }
  if (lane < cnt) {
    int s = srcsP[(size_t)n * DMAX + lane];
    float4 v = xp[s];
    ssrc[lane] = s;
    sdp[0][lane] = v.x - me.x;
    sdp[1][lane] = v.y - me.y;
    sdp[2][lane] = v.z - me.z;
  }
  __syncthreads();
  for (int k = 0; k < cnt; k += 16) {
    int ke[4] = {k + eg, k + 4 + eg, k + 8 + eg, k + 12 + eg};
    int kc[4];
    #pragma unroll
    for (int j = 0; j < 4; ++j) kc[j] = min(ke[j], cnt - 1);
    int se[4] = {ssrc[kc[0]], ssrc[kc[1]], ssrc[kc[2]], ssrc[kc[3]]};
    uint4 u[4];
    #pragma unroll
    for (int j = 0; j < 4; ++j) u[j] = *(const uint4*)&ps[(size_t)se[j] * 64 + fb * 4];
    #pragma unroll
    for (int j = 0; j < 4; ++j) {
      float dd0 = sdp[0][kc[j]], dd1 = sdp[1][kc[j]], dd2 = sdp[2][kc[j]];
      bool vv = ke[j] < cnt;
      uint uu[4] = {u[j].x, u[j].y, u[j].z, u[j].w};
      if (vv) {
        #pragma unroll
        for (int q = 0; q < 4; ++q) {
          float w0  = pdv[2*q]   + fmaf(dd0, c0[2*q],   fmaf(dd1, c1[2*q],   dd2 * c2[2*q]));
          float w1v = pdv[2*q+1] + fmaf(dd0, c0[2*q+1], fmaf(dd1, c1[2*q+1], dd2 * c2[2*q+1]));
          acc[2*q]   += fmaxf(w0  + bflo(uu[q]), 0.f);
          acc[2*q+1] += fmaxf(w1v + bfhi(uu[q]), 0.f);
        }
      }
    }
  }
  #pragma unroll
  for (int i = 0; i < 8; ++i) {
    acc[i] += __shfl_xor(acc[i], 16);
    acc[i] += __shfl_xor(acc[i], 32);
  }
  if (eg == 0) {
    uint4 o;
    o.x = packbf(acc[0], acc[1]);
    o.y = packbf(acc[2], acc[3]);
    o.z = packbf(acc[4], acc[5]);
    o.w = packbf(acc[6], acc[7]);
    *(uint4*)&hs[(size_t)n * 64 + fb * 4] = o;
  }
}

// ---------------- MFMA GEMM + relu + fused segmented pool (wave-reduced atomics) ----------------
__global__ __launch_bounds__(256) void k_mpool(
    const ushort* __restrict__ A, const ushort* __restrict__ Wt,
    const float* __restrict__ bias, const int* __restrict__ deg, const int* __restrict__ batch,
    float* __restrict__ Of, int M) {
  int t = threadIdx.x;
  int l = t & 63;
  int rl = l & 15, kg = l >> 4;
  int r = blockIdx.x * 64 + (t >> 6) * 16 + rl;
  int rc = min(r, M - 1);
  bool valid = (r < M);
  const short8* arow = (const short8*)(A + (size_t)rc * 128);
  short8 af0 = arow[kg], af1 = arow[4 + kg], af2 = arow[8 + kg], af3 = arow[12 + kg];
  float dg = valid ? (float)deg[r] : 0.f;
  int bt = batch[rc];
  int gf = __shfl(bt, 0);
  int gl = __shfl(bt, 15);
  #pragma unroll
  for (int nt = 0; nt < 8; ++nt) {
    const short8* wrow = (const short8*)(Wt + (size_t)(nt * 16 + rl) * 128);
    f32x4 acc = {0.f, 0.f, 0.f, 0.f};
    acc = MFMA_B16(wrow[kg],      af0, acc);
    acc = MFMA_B16(wrow[4 + kg],  af1, acc);
    acc = MFMA_B16(wrow[8 + kg],  af2, acc);
    acc = MFMA_B16(wrow[12 + kg], af3, acc);
    int c0 = nt * 16 + kg * 4;
    f32x4 b4 = *(const f32x4*)&bias[c0];
    float v0 = valid ? fmaxf(fmaf(dg, b4[0], acc[0]), 0.f) : 0.f;
    float v1 = valid ? fmaxf(fmaf(dg, b4[1], acc[1]), 0.f) : 0.f;
    float v2 = valid ? fmaxf(fmaf(dg, b4[2], acc[2]), 0.f) : 0.f;
    float v3 = valid ? fmaxf(fmaf(dg, b4[3], acc[3]), 0.f) : 0.f;
    for (int gg = gf; gg <= gl; ++gg) {
      bool mine = (bt == gg);
      float s0 = mine ? v0 : 0.f;
      float s1 = mine ? v1 : 0.f;
      float s2 = mine ? v2 : 0.f;
      float s3 = mine ? v3 : 0.f;
      #pragma unroll
      for (int m = 1; m <= 8; m <<= 1) {
        s0 += __shfl_xor(s0, m);
        s1 += __shfl_xor(s1, m);
        s2 += __shfl_xor(s2, m);
        s3 += __shfl_xor(s3, m);
      }
      if (rl == 0) {
        float* gp = &Of[(size_t)gg * 128 + c0];
        atomicAdd(gp + 0, s0);
        atomicAdd(gp + 1, s1);
        atomicAdd(gp + 2, s2);
        atomicAdd(gp + 3, s3);
      }
    }
  }
}

// ---------------- predictor GEMM + fused BN column-stats (atomic raw sums) ----------------
__global__ __launch_bounds__(256) void k_pgemm(
    const float* __restrict__ A, const float* __restrict__ W, float* __restrict__ O1,
    float* __restrict__ mv, int M) {
  __shared__ float As[128][36];
  int t = threadIdx.x;
  int n0 = blockIdx.x * 32;
  int j = t & 127, m = t >> 7;
  for (int idx = t; idx < 32 * 128; idx += 256) {
    int r = idx >> 7, i = idx & 127;
    int n = n0 + r;
    As[i][r] = (n < M) ? A[(size_t)n * 128 + i] : 0.f;
  }
  __syncthreads();
  float acc[16];
  #pragma unroll
  for (int r = 0; r < 16; ++r) acc[r] = 0.f;
  int rb = m * 16;
  for (int i = 0; i < 128; ++i) {
    float w = W[i * 128 + j];
    const float4* ap = reinterpret_cast<const float4*>(&As[i][rb]);
    #pragma unroll
    for (int q = 0; q < 4; ++q) {
      float4 a = ap[q];
      acc[q * 4 + 0] = fmaf(a.x, w, acc[q * 4 + 0]);
      acc[q * 4 + 1] = fmaf(a.y, w, acc[q * 4 + 1]);
      acc[q * 4 + 2] = fmaf(a.z, w, acc[q * 4 + 2]);
      acc[q * 4 + 3] = fmaf(a.w, w, acc[q * 4 + 3]);
    }
  }
  float S = 0.f, Q = 0.f;
  #pragma unroll
  for (int r = 0; r < 16; ++r) {
    int n = n0 + rb + r;
    if (n < M) {
      O1[(size_t)n * 128 + j] = acc[r];
      S += acc[r];
      Q = fmaf(acc[r], acc[r], Q);
    }
  }
  atomicAdd(&mv[j], S);
  atomicAdd(&mv[128 + j], Q);
}

// ---------------- BN-normalize (from raw sums) + relu + final linear ----------------
__global__ __launch_bounds__(256) void k_final(
    const float* __restrict__ z, const float* __restrict__ mv,
    const float* __restrict__ gamma, const float* __restrict__ beta,
    const float* __restrict__ w2, const float* __restrict__ b2,
    float* __restrict__ out, int G) {
  int wid = threadIdx.x >> 6, lane = threadIdx.x & 63;
  int r = blockIdx.x * 4 + wid;
  if (r >= G) return;
  float acc = 0.f;
  float invG = 1.f / (float)G;
  #pragma unroll
  for (int h = 0; h < 2; ++h) {
    int jj = lane + h * 64;
    float mean = mv[jj] * invG;
    float var = mv[128 + jj] * invG - mean * mean;
    float rstd = rsqrtf(var + 1e-5f);
    float v = z[(size_t)r * 128 + jj];
    float zn = fmaf((v - mean) * rstd, gamma[jj], beta[jj]);
    acc = fmaf(fmaxf(zn, 0.f), w2[jj], acc);
  }
  #pragma unroll
  for (int off = 32; off; off >>= 1) acc += __shfl_down(acc, off);
  if (lane == 0) out[r] = acc + b2[0];
}

extern "C" void kernel_launch(void* const* d_in, const int* in_sizes, int n_in,
                              void* d_out, int out_size, void* d_ws, size_t ws_size,
                              hipStream_t stream) {
  const float* x     = (const float*)d_in[0];
  const float* pos   = (const float*)d_in[1];
  const int*   eidx  = (const int*)d_in[2];
  const int*   batch = (const int*)d_in[3];
  const float* c1w1  = (const float*)d_in[4];
  const float* c1b1  = (const float*)d_in[5];
  const float* c1w2  = (const float*)d_in[6];
  const float* c1b2  = (const float*)d_in[7];
  const float* c2w1  = (const float*)d_in[8];
  const float* c2b1  = (const float*)d_in[9];
  const float* c2w2  = (const float*)d_in[10];
  const float* c2b2  = (const float*)d_in[11];
  const float* pw1   = (const float*)d_in[12];
  const float* gamma = (const float*)d_in[13];
  const float* beta  = (const float*)d_in[14];
  const float* pw2   = (const float*)d_in[15];
  const float* pb2   = (const float*)d_in[16];
  (void)n_in; (void)ws_size;

  const int N = in_sizes[0];
  const int E = in_sizes[2] / 2;
  const int G = out_size;
  const int* srcv = eidx;
  const int* dstv = eidx + E;

  char* w = (char*)d_ws;
  size_t o = 0;
  auto carve = [&](size_t bytes) { void* p = w + o; o = (o + bytes + 255) & ~(size_t)255; return p; };
  int Npad = ((N + 255) / 256) * 256;
  int* deg    = (int*)carve((size_t)Npad * 4);
  int* srcsP  = (int*)carve((size_t)N * DMAX * 4);
  float4* xp  = (float4*)carve((size_t)N * 16);
  uint*   pdb  = (uint*)carve((size_t)N * 64 * 4);    // conv2 pd bf16 packed
  uint*   psb  = (uint*)carve((size_t)N * 64 * 4);    // conv2 ps bf16 packed
  uint*   hs2  = (uint*)carve((size_t)N * 64 * 4);    // conv2 out bf16 packed
  ushort* w1t  = (ushort*)carve(16384 * 2);
  ushort* wdt  = (ushort*)carve(16384 * 2);
  ushort* wst  = (ushort*)carve(16384 * 2);
  ushort* w2t  = (ushort*)carve(16384 * 2);
  float* g    = (float*)carve((size_t)G * HID * 4);
  float* z    = (float*)carve((size_t)G * HID * 4);
  float* mv   = (float*)carve(256 * 4);

  // fused prep (zeros deg, g, mv in-kernel)
  k_prep<<<256, 256, 0, stream>>>(x, pos, c1w2, c2w1, c2w2,
                                  xp, deg, g, mv, w1t, wdt, wst, w2t, N, G, Npad);
  // XCD-sharded padded-CSR build
  int nwin = (E + ESHARD - 1) / ESHARD;
  k_build<<<nwin * 8, 256, 0, stream>>>(dstv, srcv, deg, srcsP, E);

  int gb = (N + 63) / 64;
  // fused: conv1 + (h1 -> ps, pd), fully LDS-resident
  k_front<<<gb, 512, 0, stream>>>(xp, deg, srcsP, c1w1, c1b1,
                                  w1t, wdt, wst, c1b2, c2b1, psb, pdb, N);
  k_conv2<<<N, 64, 0, stream>>>(xp, deg, srcsP, pdb, psb, c2w1 + 256 * HID, hs2);
  // conv2 second linear + relu + fused pool
  k_mpool<<<gb, 256, 0, stream>>>((const ushort*)hs2, w2t, c2b2, deg, batch, g, N);
  // predictor (pgemm also accumulates BN raw sums into mv)
  k_pgemm<<<(G + 31) / 32, 256, 0, stream>>>(g, pw1, z, mv, G);
  k_final<<<(G + 3) / 4, 256, 0, stream>>>(z, mv, gamma, beta, pw2, pb2, (float*)d_out, G);
}

// Round 17
// 193.774 us; speedup vs baseline: 1.0365x; 1.0365x over previous
//
#include <hip/hip_runtime.h>
#include <hip/hip_bf16.h>

#define HID 128
#define DMAX 64
#define ESHARD 2048

typedef unsigned int uint;
typedef unsigned short ushort;
using short8 = __attribute__((ext_vector_type(8))) short;
using f32x4  = __attribute__((ext_vector_type(4))) float;

#define MFMA_B16(a, b, c) __builtin_amdgcn_mfma_f32_16x16x32_bf16(a, b, c, 0, 0, 0)

__device__ inline ushort bf16rn(float f) {
  uint u = __float_as_uint(f);
  u += 0x7fff + ((u >> 16) & 1);
  return (ushort)(u >> 16);
}
__device__ inline uint packbf(float a, float b) {
  return (uint)bf16rn(a) | ((uint)bf16rn(b) << 16);
}
__device__ inline float bflo(uint u) { return __uint_as_float(u << 16); }
__device__ inline float bfhi(uint u) { return __uint_as_float(u & 0xffff0000u); }

// ---------------- fused prep: deg zero + g zero + mv zero + xp pack + weight cast ----------------
__global__ __launch_bounds__(256) void k_prep(
    const float* __restrict__ x, const float* __restrict__ pos,
    const float* __restrict__ c1w2, const float* __restrict__ c2w1, const float* __restrict__ c2w2,
    float4* __restrict__ xp, int* __restrict__ deg, float* __restrict__ g,
    float* __restrict__ mv,
    ushort* __restrict__ w1t, ushort* __restrict__ wdt,
    ushort* __restrict__ wst, ushort* __restrict__ w2t,
    int N, int G, int Npad) {
  int idx = blockIdx.x * 256 + threadIdx.x;
  if (idx < Npad) deg[idx] = 0;
  if (idx < G * HID) g[idx] = 0.f;
  if (idx < 256) mv[idx] = 0.f;
  if (idx < N) {
    xp[idx] = make_float4(pos[3 * idx], pos[3 * idx + 1], pos[3 * idx + 2], x[idx]);
  }
  // weight cast+transpose: 4 matrices x 16384 (grid is exactly 65536 threads)
  {
    int m = idx >> 14, e = idx & 16383;
    int c = e >> 7, k = e & 127;
    const float* src;
    ushort* dst;
    if (m == 0)      { src = c1w2;              dst = w1t; }
    else if (m == 1) { src = c2w1;              dst = wdt; }
    else if (m == 2) { src = c2w1 + 128 * 128;  dst = wst; }
    else             { src = c2w2;              dst = w2t; }
    dst[e] = bf16rn(src[k * 128 + c]);
  }
}

// ---------------- XCD-sharded padded-CSR build ----------------
// Block b (intended XCD b&7) processes window b>>3, only edges with (dst>>5)&7 == b&7.
// Each dst's counter line + srcsP lines are written from exactly one shard -> no
// cross-XCD partial-line write echo. Correctness independent of actual XCD mapping.
__global__ __launch_bounds__(256) void k_build(const int* __restrict__ dstv,
                                               const int* __restrict__ srcv,
                                               int* __restrict__ deg, int* __restrict__ srcsP,
                                               int E) {
  int shard = blockIdx.x & 7;
  int base = (blockIdx.x >> 3) * ESHARD;
  int lim = min(base + ESHARD, E);
  for (int e = base + threadIdx.x; e < lim; e += 256) {
    int d = dstv[e];
    if (((d >> 5) & 7) == shard) {
      int s = srcv[e];
      int r = atomicAdd(&deg[d], 1);
      if (r < DMAX) srcsP[(size_t)d * DMAX + r] = s;
    }
  }
}

// ---------------- conv1 edge phase (single pass, deg <= 64) ----------------
__global__ __launch_bounds__(64) void k_conv1(
    const float4* __restrict__ xp,
    const int* __restrict__ deg, const int* __restrict__ srcsP,
    const float* __restrict__ w1, const float* __restrict__ b1, uint* __restrict__ hs) {
  int n = blockIdx.x;
  int lane = threadIdx.x;
  int f0 = 2 * lane;
  __shared__ float sxs[64];
  __shared__ float sdp[3][64];
  int cnt = min(deg[n], DMAX);
  float4 me = xp[n];
  float xi = me.w;
  float2 a1 = *(const float2*)&w1[HID + f0];
  float2 a2 = *(const float2*)&w1[2 * HID + f0];
  float2 a3 = *(const float2*)&w1[3 * HID + f0];
  float2 a4 = *(const float2*)&w1[4 * HID + f0];
  float c_0 = fmaf(xi, w1[f0],     b1[f0]);
  float c_1 = fmaf(xi, w1[f0 + 1], b1[f0 + 1]);
  float acc0 = 0.f, acc1 = 0.f;
  if (lane < cnt) {
    int s = srcsP[(size_t)n * DMAX + lane];
    float4 v = xp[s];
    sxs[lane] = v.w;
    sdp[0][lane] = v.x - me.x;
    sdp[1][lane] = v.y - me.y;
    sdp[2][lane] = v.z - me.z;
  }
  __syncthreads();
  for (int k = 0; k < cnt; ++k) {
    float xj = sxs[k], d0 = sdp[0][k], d1 = sdp[1][k], d2 = sdp[2][k];
    float h0 = fmaf(xj, a1.x, fmaf(d0, a2.x, fmaf(d1, a3.x, fmaf(d2, a4.x, c_0))));
    float h1 = fmaf(xj, a1.y, fmaf(d0, a2.y, fmaf(d1, a3.y, fmaf(d2, a4.y, c_1))));
    acc0 += fmaxf(h0, 0.f);
    acc1 += fmaxf(h1, 0.f);
  }
  hs[(size_t)n * 64 + lane] = packbf(acc0, acc1);
}

// ---------------- fused GEMM, 8-wave: h1 in LDS; ps/pd staged in LDS, coalesced write-out ----------------
__global__ __launch_bounds__(512) void k_mfuse(
    const ushort* __restrict__ A, const ushort* __restrict__ W1t,
    const ushort* __restrict__ Wdt, const ushort* __restrict__ Wst,
    const float* __restrict__ b1, const float* __restrict__ bd,
    const int* __restrict__ deg,
    uint* __restrict__ psb, uint* __restrict__ pdb, int M) {
  __shared__ uint hl[64][68];   // h1 tile, later reused for ps
  __shared__ uint hd[64][68];   // pd tile
  int t = threadIdx.x;
  int l = t & 63;
  int rl = l & 15, kg = l >> 4;
  int wv = t >> 6;        // 0..7
  int rg = wv & 3;        // row group
  int cg = wv >> 2;       // col group (0..1)
  int rloc = rg * 16 + rl;
  int r = blockIdx.x * 64 + rloc;
  int rc = min(r, M - 1);
  bool valid = (r < M);
  const short8* arow = (const short8*)(A + (size_t)rc * 128);
  short8 af0 = arow[kg], af1 = arow[4 + kg], af2 = arow[8 + kg], af3 = arow[12 + kg];
  float dg = valid ? (float)deg[r] : 0.f;
  // stage 1: this wave's col-half of h1 for its 16 rows
  #pragma unroll
  for (int ntl = 0; ntl < 4; ++ntl) {
    int nt = cg * 4 + ntl;
    const short8* wrow = (const short8*)(W1t + (size_t)(nt * 16 + rl) * 128);
    f32x4 acc = {0.f, 0.f, 0.f, 0.f};
    acc = MFMA_B16(wrow[kg],      af0, acc);
    acc = MFMA_B16(wrow[4 + kg],  af1, acc);
    acc = MFMA_B16(wrow[8 + kg],  af2, acc);
    acc = MFMA_B16(wrow[12 + kg], af3, acc);
    int c0 = nt * 16 + kg * 4;
    f32x4 b4 = *(const f32x4*)&b1[c0];
    float v0 = fmaxf(fmaf(dg, b4[0], acc[0]), 0.f);
    float v1 = fmaxf(fmaf(dg, b4[1], acc[1]), 0.f);
    float v2 = fmaxf(fmaf(dg, b4[2], acc[2]), 0.f);
    float v3 = fmaxf(fmaf(dg, b4[3], acc[3]), 0.f);
    hl[rloc][(c0 >> 1)]     = packbf(v0, v1);
    hl[rloc][(c0 >> 1) + 1] = packbf(v2, v3);
  }
  __syncthreads();
  // read own-row full-K fragments of h1
  const uint* hrow = hl[rloc];
  short8 bfrag[4];
  #pragma unroll
  for (int i = 0; i < 4; ++i) bfrag[i] = *(const short8*)&hrow[i * 16 + kg * 4];
  __syncthreads();   // everyone has bfrag; hl may now be overwritten (as ps tile)
  // stage 2: compute ps/pd into LDS tiles
  #pragma unroll
  for (int ntl = 0; ntl < 4; ++ntl) {
    int nt = cg * 4 + ntl;
    const short8* wsrow = (const short8*)(Wst + (size_t)(nt * 16 + rl) * 128);
    const short8* wdrow = (const short8*)(Wdt + (size_t)(nt * 16 + rl) * 128);
    f32x4 accS = {0.f, 0.f, 0.f, 0.f};
    f32x4 accD = {0.f, 0.f, 0.f, 0.f};
    accS = MFMA_B16(wsrow[kg],      bfrag[0], accS);
    accS = MFMA_B16(wsrow[4 + kg],  bfrag[1], accS);
    accS = MFMA_B16(wsrow[8 + kg],  bfrag[2], accS);
    accS = MFMA_B16(wsrow[12 + kg], bfrag[3], accS);
    accD = MFMA_B16(wdrow[kg],      bfrag[0], accD);
    accD = MFMA_B16(wdrow[4 + kg],  bfrag[1], accD);
    accD = MFMA_B16(wdrow[8 + kg],  bfrag[2], accD);
    accD = MFMA_B16(wdrow[12 + kg], bfrag[3], accD);
    int c0 = nt * 16 + kg * 4;
    f32x4 b4 = *(const f32x4*)&bd[c0];
    hl[rloc][(c0 >> 1)]     = packbf(accS[0], accS[1]);
    hl[rloc][(c0 >> 1) + 1] = packbf(accS[2], accS[3]);
    hd[rloc][(c0 >> 1)]     = packbf(accD[0] + b4[0], accD[1] + b4[1]);
    hd[rloc][(c0 >> 1) + 1] = packbf(accD[2] + b4[2], accD[3] + b4[3]);
  }
  __syncthreads();
  // coalesced copy-out: 256B aligned segments per row
  int rbase = blockIdx.x * 64;
  #pragma unroll
  for (int idx = t; idx < 64 * 16; idx += 512) {
    int row = idx >> 4, c4 = (idx & 15) * 4;
    int gr = rbase + row;
    if (gr < M) {
      *(uint4*)&psb[(size_t)gr * 64 + c4] = *(const uint4*)&hl[row][c4];
      *(uint4*)&pdb[(size_t)gr * 64 + c4] = *(const uint4*)&hd[row][c4];
    }
  }
}

// ---------------- conv2 edge phase: dwordx4 ps gather, 16 edges in flight ----------------
__global__ __launch_bounds__(64) void k_conv2(
    const float4* __restrict__ xp,
    const int* __restrict__ deg, const int* __restrict__ srcsP,
    const uint* __restrict__ pdb, const uint* __restrict__ ps,
    const float* __restrict__ wc, uint* __restrict__ hs) {
  int n = blockIdx.x;
  int lane = threadIdx.x;
  int eg = lane >> 4;
  int fb = lane & 15;
  int f0 = 8 * fb;
  __shared__ int ssrc[64];
  __shared__ float sdp[3][64];
  int cnt = min(deg[n], DMAX);
  float4 me = xp[n];
  float c0[8], c1[8], c2[8], pdv[8], acc[8];
  uint4 pdu = *(const uint4*)&pdb[(size_t)n * 64 + fb * 4];
  uint pdua[4] = {pdu.x, pdu.y, pdu.z, pdu.w};
  #pragma unroll
  for (int i = 0; i < 4; ++i) {
    pdv[2 * i]     = bflo(pdua[i]);
    pdv[2 * i + 1] = bfhi(pdua[i]);
  }
  #pragma unroll
  for (int i = 0; i < 8; ++i) {
    c0[i]  = wc[f0 + i];
    c1[i]  = wc[HID + f0 + i];
    c2[i]  = wc[2 * HID + f0 + i];
    acc[i] = 0.f;
  }
  if (lane < cnt) {
    int s = srcsP[(size_t)n * DMAX + lane];
    float4 v = xp[s];
    ssrc[lane] = s;
    sdp[0][lane] = v.x - me.x;
    sdp[1][lane] = v.y - me.y;
    sdp[2][lane] = v.z - me.z;
  }
  __syncthreads();
  for (int k = 0; k < cnt; k += 16) {
    int ke[4] = {k + eg, k + 4 + eg, k + 8 + eg, k + 12 + eg};
    int kc[4];
    #pragma unroll
    for (int j = 0; j < 4; ++j) kc[j] = min(ke[j], cnt - 1);
    int se[4] = {ssrc[kc[0]], ssrc[kc[1]], ssrc[kc[2]], ssrc[kc[3]]};
    uint4 u[4];
    #pragma unroll
    for (int j = 0; j < 4; ++j) u[j] = *(const uint4*)&ps[(size_t)se[j] * 64 + fb * 4];
    #pragma unroll
    for (int j = 0; j < 4; ++j) {
      float dd0 = sdp[0][kc[j]], dd1 = sdp[1][kc[j]], dd2 = sdp[2][kc[j]];
      bool vv = ke[j] < cnt;
      uint uu[4] = {u[j].x, u[j].y, u[j].z, u[j].w};
      if (vv) {
        #pragma unroll
        for (int q = 0; q < 4; ++q) {
          float w0  = pdv[2*q]   + fmaf(dd0, c0[2*q],   fmaf(dd1, c1[2*q],   dd2 * c2[2*q]));
          float w1v = pdv[2*q+1] + fmaf(dd0, c0[2*q+1], fmaf(dd1, c1[2*q+1], dd2 * c2[2*q+1]));
          acc[2*q]   += fmaxf(w0  + bflo(uu[q]), 0.f);
          acc[2*q+1] += fmaxf(w1v + bfhi(uu[q]), 0.f);
        }
      }
    }
  }
  #pragma unroll
  for (int i = 0; i < 8; ++i) {
    acc[i] += __shfl_xor(acc[i], 16);
    acc[i] += __shfl_xor(acc[i], 32);
  }
  if (eg == 0) {
    uint4 o;
    o.x = packbf(acc[0], acc[1]);
    o.y = packbf(acc[2], acc[3]);
    o.z = packbf(acc[4], acc[5]);
    o.w = packbf(acc[6], acc[7]);
    *(uint4*)&hs[(size_t)n * 64 + fb * 4] = o;
  }
}

// ---------------- MFMA GEMM + relu + fused segmented pool (wave-reduced atomics) ----------------
__global__ __launch_bounds__(256) void k_mpool(
    const ushort* __restrict__ A, const ushort* __restrict__ Wt,
    const float* __restrict__ bias, const int* __restrict__ deg, const int* __restrict__ batch,
    float* __restrict__ Of, int M) {
  int t = threadIdx.x;
  int l = t & 63;
  int rl = l & 15, kg = l >> 4;
  int r = blockIdx.x * 64 + (t >> 6) * 16 + rl;
  int rc = min(r, M - 1);
  bool valid = (r < M);
  const short8* arow = (const short8*)(A + (size_t)rc * 128);
  short8 af0 = arow[kg], af1 = arow[4 + kg], af2 = arow[8 + kg], af3 = arow[12 + kg];
  float dg = valid ? (float)deg[r] : 0.f;
  int bt = batch[rc];
  int gf = __shfl(bt, 0);
  int gl = __shfl(bt, 15);
  #pragma unroll
  for (int nt = 0; nt < 8; ++nt) {
    const short8* wrow = (const short8*)(Wt + (size_t)(nt * 16 + rl) * 128);
    f32x4 acc = {0.f, 0.f, 0.f, 0.f};
    acc = MFMA_B16(wrow[kg],      af0, acc);
    acc = MFMA_B16(wrow[4 + kg],  af1, acc);
    acc = MFMA_B16(wrow[8 + kg],  af2, acc);
    acc = MFMA_B16(wrow[12 + kg], af3, acc);
    int c0 = nt * 16 + kg * 4;
    f32x4 b4 = *(const f32x4*)&bias[c0];
    float v0 = valid ? fmaxf(fmaf(dg, b4[0], acc[0]), 0.f) : 0.f;
    float v1 = valid ? fmaxf(fmaf(dg, b4[1], acc[1]), 0.f) : 0.f;
    float v2 = valid ? fmaxf(fmaf(dg, b4[2], acc[2]), 0.f) : 0.f;
    float v3 = valid ? fmaxf(fmaf(dg, b4[3], acc[3]), 0.f) : 0.f;
    for (int gg = gf; gg <= gl; ++gg) {
      bool mine = (bt == gg);
      float s0 = mine ? v0 : 0.f;
      float s1 = mine ? v1 : 0.f;
      float s2 = mine ? v2 : 0.f;
      float s3 = mine ? v3 : 0.f;
      #pragma unroll
      for (int m = 1; m <= 8; m <<= 1) {
        s0 += __shfl_xor(s0, m);
        s1 += __shfl_xor(s1, m);
        s2 += __shfl_xor(s2, m);
        s3 += __shfl_xor(s3, m);
      }
      if (rl == 0) {
        float* gp = &Of[(size_t)gg * 128 + c0];
        atomicAdd(gp + 0, s0);
        atomicAdd(gp + 1, s1);
        atomicAdd(gp + 2, s2);
        atomicAdd(gp + 3, s3);
      }
    }
  }
}

// ---------------- predictor GEMM + fused BN column-stats (atomic raw sums) ----------------
__global__ __launch_bounds__(256) void k_pgemm(
    const float* __restrict__ A, const float* __restrict__ W, float* __restrict__ O1,
    float* __restrict__ mv, int M) {
  __shared__ float As[128][36];
  int t = threadIdx.x;
  int n0 = blockIdx.x * 32;
  int j = t & 127, m = t >> 7;
  for (int idx = t; idx < 32 * 128; idx += 256) {
    int r = idx >> 7, i = idx & 127;
    int n = n0 + r;
    As[i][r] = (n < M) ? A[(size_t)n * 128 + i] : 0.f;
  }
  __syncthreads();
  float acc[16];
  #pragma unroll
  for (int r = 0; r < 16; ++r) acc[r] = 0.f;
  int rb = m * 16;
  for (int i = 0; i < 128; ++i) {
    float w = W[i * 128 + j];
    const float4* ap = reinterpret_cast<const float4*>(&As[i][rb]);
    #pragma unroll
    for (int q = 0; q < 4; ++q) {
      float4 a = ap[q];
      acc[q * 4 + 0] = fmaf(a.x, w, acc[q * 4 + 0]);
      acc[q * 4 + 1] = fmaf(a.y, w, acc[q * 4 + 1]);
      acc[q * 4 + 2] = fmaf(a.z, w, acc[q * 4 + 2]);
      acc[q * 4 + 3] = fmaf(a.w, w, acc[q * 4 + 3]);
    }
  }
  float S = 0.f, Q = 0.f;
  #pragma unroll
  for (int r = 0; r < 16; ++r) {
    int n = n0 + rb + r;
    if (n < M) {
      O1[(size_t)n * 128 + j] = acc[r];
      S += acc[r];
      Q = fmaf(acc[r], acc[r], Q);
    }
  }
  atomicAdd(&mv[j], S);
  atomicAdd(&mv[128 + j], Q);
}

// ---------------- BN-normalize (from raw sums) + relu + final linear ----------------
__global__ __launch_bounds__(256) void k_final(
    const float* __restrict__ z, const float* __restrict__ mv,
    const float* __restrict__ gamma, const float* __restrict__ beta,
    const float* __restrict__ w2, const float* __restrict__ b2,
    float* __restrict__ out, int G) {
  int wid = threadIdx.x >> 6, lane = threadIdx.x & 63;
  int r = blockIdx.x * 4 + wid;
  if (r >= G) return;
  float acc = 0.f;
  float invG = 1.f / (float)G;
  #pragma unroll
  for (int h = 0; h < 2; ++h) {
    int jj = lane + h * 64;
    float mean = mv[jj] * invG;
    float var = mv[128 + jj] * invG - mean * mean;
    float rstd = rsqrtf(var + 1e-5f);
    float v = z[(size_t)r * 128 + jj];
    float zn = fmaf((v - mean) * rstd, gamma[jj], beta[jj]);
    acc = fmaf(fmaxf(zn, 0.f), w2[jj], acc);
  }
  #pragma unroll
  for (int off = 32; off; off >>= 1) acc += __shfl_down(acc, off);
  if (lane == 0) out[r] = acc + b2[0];
}

extern "C" void kernel_launch(void* const* d_in, const int* in_sizes, int n_in,
                              void* d_out, int out_size, void* d_ws, size_t ws_size,
                              hipStream_t stream) {
  const float* x     = (const float*)d_in[0];
  const float* pos   = (const float*)d_in[1];
  const int*   eidx  = (const int*)d_in[2];
  const int*   batch = (const int*)d_in[3];
  const float* c1w1  = (const float*)d_in[4];
  const float* c1b1  = (const float*)d_in[5];
  const float* c1w2  = (const float*)d_in[6];
  const float* c1b2  = (const float*)d_in[7];
  const float* c2w1  = (const float*)d_in[8];
  const float* c2b1  = (const float*)d_in[9];
  const float* c2w2  = (const float*)d_in[10];
  const float* c2b2  = (const float*)d_in[11];
  const float* pw1   = (const float*)d_in[12];
  const float* gamma = (const float*)d_in[13];
  const float* beta  = (const float*)d_in[14];
  const float* pw2   = (const float*)d_in[15];
  const float* pb2   = (const float*)d_in[16];
  (void)n_in; (void)ws_size;

  const int N = in_sizes[0];
  const int E = in_sizes[2] / 2;
  const int G = out_size;
  const int* srcv = eidx;
  const int* dstv = eidx + E;

  char* w = (char*)d_ws;
  size_t o = 0;
  auto carve = [&](size_t bytes) { void* p = w + o; o = (o + bytes + 255) & ~(size_t)255; return p; };
  int Npad = ((N + 255) / 256) * 256;
  int* deg    = (int*)carve((size_t)Npad * 4);
  int* srcsP  = (int*)carve((size_t)N * DMAX * 4);
  float4* xp  = (float4*)carve((size_t)N * 16);
  uint*   hs1  = (uint*)carve((size_t)N * 64 * 4);    // conv1 out, bf16 packed
  uint*   pdb  = (uint*)carve((size_t)N * 64 * 4);    // conv2 pd bf16 packed
  uint*   psb  = (uint*)carve((size_t)N * 64 * 4);    // conv2 ps bf16 packed
  uint*   hs2  = (uint*)carve((size_t)N * 64 * 4);    // conv2 out bf16 packed
  ushort* w1t  = (ushort*)carve(16384 * 2);
  ushort* wdt  = (ushort*)carve(16384 * 2);
  ushort* wst  = (ushort*)carve(16384 * 2);
  ushort* w2t  = (ushort*)carve(16384 * 2);
  float* g    = (float*)carve((size_t)G * HID * 4);
  float* z    = (float*)carve((size_t)G * HID * 4);
  float* mv   = (float*)carve(256 * 4);

  // fused prep (zeros deg, g, mv in-kernel)
  k_prep<<<256, 256, 0, stream>>>(x, pos, c1w2, c2w1, c2w2,
                                  xp, deg, g, mv, w1t, wdt, wst, w2t, N, G, Npad);
  // XCD-sharded padded-CSR build
  int nwin = (E + ESHARD - 1) / ESHARD;
  k_build<<<nwin * 8, 256, 0, stream>>>(dstv, srcv, deg, srcsP, E);

  int gb = (N + 63) / 64;
  // conv1
  k_conv1<<<N, 64, 0, stream>>>(xp, deg, srcsP, c1w1, c1b1, hs1);
  // fused: h1 (LDS-resident) -> pd, ps
  k_mfuse<<<gb, 512, 0, stream>>>((const ushort*)hs1, w1t, wdt, wst, c1b2, c2b1, deg,
                                  psb, pdb, N);
  k_conv2<<<N, 64, 0, stream>>>(xp, deg, srcsP, pdb, psb, c2w1 + 256 * HID, hs2);
  // conv2 second linear + relu + fused pool
  k_mpool<<<gb, 256, 0, stream>>>((const ushort*)hs2, w2t, c2b2, deg, batch, g, N);
  // predictor (pgemm also accumulates BN raw sums into mv)
  k_pgemm<<<(G + 31) / 32, 256, 0, stream>>>(g, pw1, z, mv, G);
  k_final<<<(G + 3) / 4, 256, 0, stream>>>(z, mv, gamma, beta, pw2, pb2, (float*)d_out, G);
}

// Round 18
// 166.761 us; speedup vs baseline: 1.2044x; 1.1620x over previous
//
#include <hip/hip_runtime.h>
#include <hip/hip_bf16.h>

#define HID 128
#define DMAX 64
#define ESHARD 2048

typedef unsigned int uint;
typedef unsigned short ushort;
using short8 = __attribute__((ext_vector_type(8))) short;
using f32x4  = __attribute__((ext_vector_type(4))) float;

#define MFMA_B16(a, b, c) __builtin_amdgcn_mfma_f32_16x16x32_bf16(a, b, c, 0, 0, 0)

__device__ inline ushort bf16rn(float f) {
  uint u = __float_as_uint(f);
  u += 0x7fff + ((u >> 16) & 1);
  return (ushort)(u >> 16);
}
__device__ inline uint packbf(float a, float b) {
  return (uint)bf16rn(a) | ((uint)bf16rn(b) << 16);
}
__device__ inline float bflo(uint u) { return __uint_as_float(u << 16); }
__device__ inline float bfhi(uint u) { return __uint_as_float(u & 0xffff0000u); }

// ---------------- fused prep: deg zero + g zero + mv zero + xp pack + weight cast ----------------
__global__ __launch_bounds__(256) void k_prep(
    const float* __restrict__ x, const float* __restrict__ pos,
    const float* __restrict__ c1w2, const float* __restrict__ c2w1, const float* __restrict__ c2w2,
    float4* __restrict__ xp, int* __restrict__ deg, float* __restrict__ g,
    float* __restrict__ mv,
    ushort* __restrict__ w1t, ushort* __restrict__ wdt,
    ushort* __restrict__ wst, ushort* __restrict__ w2t,
    int N, int G, int Npad) {
  int idx = blockIdx.x * 256 + threadIdx.x;
  if (idx < Npad) deg[idx] = 0;
  if (idx < G * HID) g[idx] = 0.f;
  if (idx < 256) mv[idx] = 0.f;
  if (idx < N) {
    xp[idx] = make_float4(pos[3 * idx], pos[3 * idx + 1], pos[3 * idx + 2], x[idx]);
  }
  // weight cast+transpose: 4 matrices x 16384 (grid is exactly 65536 threads)
  {
    int m = idx >> 14, e = idx & 16383;
    int c = e >> 7, k = e & 127;
    const float* src;
    ushort* dst;
    if (m == 0)      { src = c1w2;              dst = w1t; }
    else if (m == 1) { src = c2w1;              dst = wdt; }
    else if (m == 2) { src = c2w1 + 128 * 128;  dst = wst; }
    else             { src = c2w2;              dst = w2t; }
    dst[e] = bf16rn(src[k * 128 + c]);
  }
}

// ---------------- XCD-sharded padded-CSR build ----------------
__global__ __launch_bounds__(256) void k_build(const int* __restrict__ dstv,
                                               const int* __restrict__ srcv,
                                               int* __restrict__ deg, int* __restrict__ srcsP,
                                               int E) {
  int shard = blockIdx.x & 7;
  int base = (blockIdx.x >> 3) * ESHARD;
  int lim = min(base + ESHARD, E);
  for (int e = base + threadIdx.x; e < lim; e += 256) {
    int d = dstv[e];
    if (((d >> 5) & 7) == shard) {
      int s = srcv[e];
      int r = atomicAdd(&deg[d], 1);
      if (r < DMAX) srcsP[(size_t)d * DMAX + r] = s;
    }
  }
}

// ---------------- conv1 edge phase (single pass, deg <= 64) ----------------
__global__ __launch_bounds__(64) void k_conv1(
    const float4* __restrict__ xp,
    const int* __restrict__ deg, const int* __restrict__ srcsP,
    const float* __restrict__ w1, const float* __restrict__ b1, uint* __restrict__ hs) {
  int n = blockIdx.x;
  int lane = threadIdx.x;
  int f0 = 2 * lane;
  __shared__ float sxs[64];
  __shared__ float sdp[3][64];
  int cnt = min(deg[n], DMAX);
  float4 me = xp[n];
  float xi = me.w;
  float2 a1 = *(const float2*)&w1[HID + f0];
  float2 a2 = *(const float2*)&w1[2 * HID + f0];
  float2 a3 = *(const float2*)&w1[3 * HID + f0];
  float2 a4 = *(const float2*)&w1[4 * HID + f0];
  float c_0 = fmaf(xi, w1[f0],     b1[f0]);
  float c_1 = fmaf(xi, w1[f0 + 1], b1[f0 + 1]);
  float acc0 = 0.f, acc1 = 0.f;
  if (lane < cnt) {
    int s = srcsP[(size_t)n * DMAX + lane];
    float4 v = xp[s];
    sxs[lane] = v.w;
    sdp[0][lane] = v.x - me.x;
    sdp[1][lane] = v.y - me.y;
    sdp[2][lane] = v.z - me.z;
  }
  __syncthreads();
  for (int k = 0; k < cnt; ++k) {
    float xj = sxs[k], d0 = sdp[0][k], d1 = sdp[1][k], d2 = sdp[2][k];
    float h0 = fmaf(xj, a1.x, fmaf(d0, a2.x, fmaf(d1, a3.x, fmaf(d2, a4.x, c_0))));
    float h1 = fmaf(xj, a1.y, fmaf(d0, a2.y, fmaf(d1, a3.y, fmaf(d2, a4.y, c_1))));
    acc0 += fmaxf(h0, 0.f);
    acc1 += fmaxf(h1, 0.f);
  }
  hs[(size_t)n * 64 + lane] = packbf(acc0, acc1);
}

// ---------------- fused GEMM, 64-rows-per-wave: weight frags reused across 4 row-groups ----------------
// 512 threads = 8 waves = 2 row-supergroups x 4 col-tiles; 128 rows/block.
// Stage 1: wave (rs,ct) computes h1 cols [ct*32,ct*32+32) for rows rs*64..rs*64+63.
// Stage 2: ct 0-1 -> ps (Wst) col-halves, ct 2-3 -> pd (Wdt + bd) col-halves.
__global__ __launch_bounds__(512) void k_mfuse(
    const ushort* __restrict__ A, const ushort* __restrict__ W1t,
    const ushort* __restrict__ Wdt, const ushort* __restrict__ Wst,
    const float* __restrict__ b1, const float* __restrict__ bd,
    const int* __restrict__ deg,
    uint* __restrict__ psb, uint* __restrict__ pdb, int M) {
  __shared__ uint hl[128][68];   // hsum/h1 tile, later reused for ps
  __shared__ uint hd[128][68];   // pd tile
  int t = threadIdx.x;
  int l = t & 63;
  int rl = l & 15, kg = l >> 4;
  int wv = t >> 6;        // 0..7
  int rs = wv >> 2;       // row supergroup 0..1
  int ct = wv & 3;        // col tile 0..3
  int rowbase = blockIdx.x * 128 + rs * 64;
  // A-fragments for 4 row-groups (64 rows per wave)
  short8 af[4][4];
  float dgv[4];
  #pragma unroll
  for (int rg = 0; rg < 4; ++rg) {
    int r = rowbase + rg * 16 + rl;
    int rc = min(r, M - 1);
    const short8* arow = (const short8*)(A + (size_t)rc * 128);
    #pragma unroll
    for (int k = 0; k < 4; ++k) af[rg][k] = arow[4 * k + kg];
    dgv[rg] = (r < M) ? (float)deg[r] : 0.f;
  }
  // stage 1: h1 = relu(hsum@W1 + deg*b1), this wave's 32 cols x 64 rows
  #pragma unroll
  for (int j = 0; j < 2; ++j) {
    int nt = ct * 2 + j;
    const short8* wrow = (const short8*)(W1t + (size_t)(nt * 16 + rl) * 128);
    short8 wf[4];
    #pragma unroll
    for (int k = 0; k < 4; ++k) wf[k] = wrow[4 * k + kg];
    int c0 = nt * 16 + kg * 4;
    f32x4 b4 = *(const f32x4*)&b1[c0];
    #pragma unroll
    for (int rg = 0; rg < 4; ++rg) {
      f32x4 acc = {0.f, 0.f, 0.f, 0.f};
      acc = MFMA_B16(wf[0], af[rg][0], acc);
      acc = MFMA_B16(wf[1], af[rg][1], acc);
      acc = MFMA_B16(wf[2], af[rg][2], acc);
      acc = MFMA_B16(wf[3], af[rg][3], acc);
      int rloc = rs * 64 + rg * 16 + rl;
      float v0 = fmaxf(fmaf(dgv[rg], b4[0], acc[0]), 0.f);
      float v1 = fmaxf(fmaf(dgv[rg], b4[1], acc[1]), 0.f);
      float v2 = fmaxf(fmaf(dgv[rg], b4[2], acc[2]), 0.f);
      float v3 = fmaxf(fmaf(dgv[rg], b4[3], acc[3]), 0.f);
      hl[rloc][(c0 >> 1)]     = packbf(v0, v1);
      hl[rloc][(c0 >> 1) + 1] = packbf(v2, v3);
    }
  }
  __syncthreads();
  // read h1 full-K fragments for own 64 rows (reuse af)
  #pragma unroll
  for (int rg = 0; rg < 4; ++rg) {
    const uint* hrow = hl[rs * 64 + rg * 16 + rl];
    #pragma unroll
    for (int k = 0; k < 4; ++k) af[rg][k] = *(const short8*)&hrow[k * 16 + kg * 4];
  }
  __syncthreads();   // everyone has frags; hl may be overwritten as ps tile
  // stage 2: ct 0-1 -> S (ps), ct 2-3 -> D (pd)
  bool isD = (ct >> 1) != 0;
  int ntb = (ct & 1) * 4;
  const ushort* Wm = isD ? Wdt : Wst;
  #pragma unroll
  for (int jj = 0; jj < 4; ++jj) {
    int nt = ntb + jj;
    const short8* wrow = (const short8*)(Wm + (size_t)(nt * 16 + rl) * 128);
    short8 wf[4];
    #pragma unroll
    for (int k = 0; k < 4; ++k) wf[k] = wrow[4 * k + kg];
    int c0 = nt * 16 + kg * 4;
    f32x4 b4 = {0.f, 0.f, 0.f, 0.f};
    if (isD) b4 = *(const f32x4*)&bd[c0];
    #pragma unroll
    for (int rg = 0; rg < 4; ++rg) {
      f32x4 acc = {0.f, 0.f, 0.f, 0.f};
      acc = MFMA_B16(wf[0], af[rg][0], acc);
      acc = MFMA_B16(wf[1], af[rg][1], acc);
      acc = MFMA_B16(wf[2], af[rg][2], acc);
      acc = MFMA_B16(wf[3], af[rg][3], acc);
      int rloc = rs * 64 + rg * 16 + rl;
      uint lo = packbf(acc[0] + b4[0], acc[1] + b4[1]);
      uint hi = packbf(acc[2] + b4[2], acc[3] + b4[3]);
      if (isD) {
        hd[rloc][(c0 >> 1)]     = lo;
        hd[rloc][(c0 >> 1) + 1] = hi;
      } else {
        hl[rloc][(c0 >> 1)]     = lo;
        hl[rloc][(c0 >> 1) + 1] = hi;
      }
    }
  }
  __syncthreads();
  // coalesced copy-out: 256B aligned segments per row
  int rb2 = blockIdx.x * 128;
  #pragma unroll
  for (int idx = t; idx < 128 * 16; idx += 512) {
    int row = idx >> 4, c4 = (idx & 15) * 4;
    int gr = rb2 + row;
    if (gr < M) {
      *(uint4*)&psb[(size_t)gr * 64 + c4] = *(const uint4*)&hl[row][c4];
      *(uint4*)&pdb[(size_t)gr * 64 + c4] = *(const uint4*)&hd[row][c4];
    }
  }
}

// ---------------- conv2 edge phase: dwordx4 ps gather, 16 edges in flight ----------------
__global__ __launch_bounds__(64) void k_conv2(
    const float4* __restrict__ xp,
    const int* __restrict__ deg, const int* __restrict__ srcsP,
    const uint* __restrict__ pdb, const uint* __restrict__ ps,
    const float* __restrict__ wc, uint* __restrict__ hs) {
  int n = blockIdx.x;
  int lane = threadIdx.x;
  int eg = lane >> 4;
  int fb = lane & 15;
  int f0 = 8 * fb;
  __shared__ int ssrc[64];
  __shared__ float sdp[3][64];
  int cnt = min(deg[n], DMAX);
  float4 me = xp[n];
  float c0[8], c1[8], c2[8], pdv[8], acc[8];
  uint4 pdu = *(const uint4*)&pdb[(size_t)n * 64 + fb * 4];
  uint pdua[4] = {pdu.x, pdu.y, pdu.z, pdu.w};
  #pragma unroll
  for (int i = 0; i < 4; ++i) {
    pdv[2 * i]     = bflo(pdua[i]);
    pdv[2 * i + 1] = bfhi(pdua[i]);
  }
  #pragma unroll
  for (int i = 0; i < 8; ++i) {
    c0[i]  = wc[f0 + i];
    c1[i]  = wc[HID + f0 + i];
    c2[i]  = wc[2 * HID + f0 + i];
    acc[i] = 0.f;
  }
  if (lane < cnt) {
    int s = srcsP[(size_t)n * DMAX + lane];
    float4 v = xp[s];
    ssrc[lane] = s;
    sdp[0][lane] = v.x - me.x;
    sdp[1][lane] = v.y - me.y;
    sdp[2][lane] = v.z - me.z;
  }
  __syncthreads();
  for (int k = 0; k < cnt; k += 16) {
    int ke[4] = {k + eg, k + 4 + eg, k + 8 + eg, k + 12 + eg};
    int kc[4];
    #pragma unroll
    for (int j = 0; j < 4; ++j) kc[j] = min(ke[j], cnt - 1);
    int se[4] = {ssrc[kc[0]], ssrc[kc[1]], ssrc[kc[2]], ssrc[kc[3]]};
    uint4 u[4];
    #pragma unroll
    for (int j = 0; j < 4; ++j) u[j] = *(const uint4*)&ps[(size_t)se[j] * 64 + fb * 4];
    #pragma unroll
    for (int j = 0; j < 4; ++j) {
      float dd0 = sdp[0][kc[j]], dd1 = sdp[1][kc[j]], dd2 = sdp[2][kc[j]];
      bool vv = ke[j] < cnt;
      uint uu[4] = {u[j].x, u[j].y, u[j].z, u[j].w};
      if (vv) {
        #pragma unroll
        for (int q = 0; q < 4; ++q) {
          float w0  = pdv[2*q]   + fmaf(dd0, c0[2*q],   fmaf(dd1, c1[2*q],   dd2 * c2[2*q]));
          float w1v = pdv[2*q+1] + fmaf(dd0, c0[2*q+1], fmaf(dd1, c1[2*q+1], dd2 * c2[2*q+1]));
          acc[2*q]   += fmaxf(w0  + bflo(uu[q]), 0.f);
          acc[2*q+1] += fmaxf(w1v + bfhi(uu[q]), 0.f);
        }
      }
    }
  }
  #pragma unroll
  for (int i = 0; i < 8; ++i) {
    acc[i] += __shfl_xor(acc[i], 16);
    acc[i] += __shfl_xor(acc[i], 32);
  }
  if (eg == 0) {
    uint4 o;
    o.x = packbf(acc[0], acc[1]);
    o.y = packbf(acc[2], acc[3]);
    o.z = packbf(acc[4], acc[5]);
    o.w = packbf(acc[6], acc[7]);
    *(uint4*)&hs[(size_t)n * 64 + fb * 4] = o;
  }
}

// ---------------- MFMA GEMM + relu + fused segmented pool (wave-reduced atomics) ----------------
__global__ __launch_bounds__(256) void k_mpool(
    const ushort* __restrict__ A, const ushort* __restrict__ Wt,
    const float* __restrict__ bias, const int* __restrict__ deg, const int* __restrict__ batch,
    float* __restrict__ Of, int M) {
  int t = threadIdx.x;
  int l = t & 63;
  int rl = l & 15, kg = l >> 4;
  int r = blockIdx.x * 64 + (t >> 6) * 16 + rl;
  int rc = min(r, M - 1);
  bool valid = (r < M);
  const short8* arow = (const short8*)(A + (size_t)rc * 128);
  short8 af0 = arow[kg], af1 = arow[4 + kg], af2 = arow[8 + kg], af3 = arow[12 + kg];
  float dg = valid ? (float)deg[r] : 0.f;
  int bt = batch[rc];
  int gf = __shfl(bt, 0);
  int gl = __shfl(bt, 15);
  #pragma unroll
  for (int nt = 0; nt < 8; ++nt) {
    const short8* wrow = (const short8*)(Wt + (size_t)(nt * 16 + rl) * 128);
    f32x4 acc = {0.f, 0.f, 0.f, 0.f};
    acc = MFMA_B16(wrow[kg],      af0, acc);
    acc = MFMA_B16(wrow[4 + kg],  af1, acc);
    acc = MFMA_B16(wrow[8 + kg],  af2, acc);
    acc = MFMA_B16(wrow[12 + kg], af3, acc);
    int c0 = nt * 16 + kg * 4;
    f32x4 b4 = *(const f32x4*)&bias[c0];
    float v0 = valid ? fmaxf(fmaf(dg, b4[0], acc[0]), 0.f) : 0.f;
    float v1 = valid ? fmaxf(fmaf(dg, b4[1], acc[1]), 0.f) : 0.f;
    float v2 = valid ? fmaxf(fmaf(dg, b4[2], acc[2]), 0.f) : 0.f;
    float v3 = valid ? fmaxf(fmaf(dg, b4[3], acc[3]), 0.f) : 0.f;
    for (int gg = gf; gg <= gl; ++gg) {
      bool mine = (bt == gg);
      float s0 = mine ? v0 : 0.f;
      float s1 = mine ? v1 : 0.f;
      float s2 = mine ? v2 : 0.f;
      float s3 = mine ? v3 : 0.f;
      #pragma unroll
      for (int m = 1; m <= 8; m <<= 1) {
        s0 += __shfl_xor(s0, m);
        s1 += __shfl_xor(s1, m);
        s2 += __shfl_xor(s2, m);
        s3 += __shfl_xor(s3, m);
      }
      if (rl == 0) {
        float* gp = &Of[(size_t)gg * 128 + c0];
        atomicAdd(gp + 0, s0);
        atomicAdd(gp + 1, s1);
        atomicAdd(gp + 2, s2);
        atomicAdd(gp + 3, s3);
      }
    }
  }
}

// ---------------- predictor GEMM + fused BN column-stats (atomic raw sums) ----------------
__global__ __launch_bounds__(256) void k_pgemm(
    const float* __restrict__ A, const float* __restrict__ W, float* __restrict__ O1,
    float* __restrict__ mv, int M) {
  __shared__ float As[128][36];
  int t = threadIdx.x;
  int n0 = blockIdx.x * 32;
  int j = t & 127, m = t >> 7;
  for (int idx = t; idx < 32 * 128; idx += 256) {
    int r = idx >> 7, i = idx & 127;
    int n = n0 + r;
    As[i][r] = (n < M) ? A[(size_t)n * 128 + i] : 0.f;
  }
  __syncthreads();
  float acc[16];
  #pragma unroll
  for (int r = 0; r < 16; ++r) acc[r] = 0.f;
  int rb = m * 16;
  for (int i = 0; i < 128; ++i) {
    float w = W[i * 128 + j];
    const float4* ap = reinterpret_cast<const float4*>(&As[i][rb]);
    #pragma unroll
    for (int q = 0; q < 4; ++q) {
      float4 a = ap[q];
      acc[q * 4 + 0] = fmaf(a.x, w, acc[q * 4 + 0]);
      acc[q * 4 + 1] = fmaf(a.y, w, acc[q * 4 + 1]);
      acc[q * 4 + 2] = fmaf(a.z, w, acc[q * 4 + 2]);
      acc[q * 4 + 3] = fmaf(a.w, w, acc[q * 4 + 3]);
    }
  }
  float S = 0.f, Q = 0.f;
  #pragma unroll
  for (int r = 0; r < 16; ++r) {
    int n = n0 + rb + r;
    if (n < M) {
      O1[(size_t)n * 128 + j] = acc[r];
      S += acc[r];
      Q = fmaf(acc[r], acc[r], Q);
    }
  }
  atomicAdd(&mv[j], S);
  atomicAdd(&mv[128 + j], Q);
}

// ---------------- BN-normalize (from raw sums) + relu + final linear ----------------
__global__ __launch_bounds__(256) void k_final(
    const float* __restrict__ z, const float* __restrict__ mv,
    const float* __restrict__ gamma, const float* __restrict__ beta,
    const float* __restrict__ w2, const float* __restrict__ b2,
    float* __restrict__ out, int G) {
  int wid = threadIdx.x >> 6, lane = threadIdx.x & 63;
  int r = blockIdx.x * 4 + wid;
  if (r >= G) return;
  float acc = 0.f;
  float invG = 1.f / (float)G;
  #pragma unroll
  for (int h = 0; h < 2; ++h) {
    int jj = lane + h * 64;
    float mean = mv[jj] * invG;
    float var = mv[128 + jj] * invG - mean * mean;
    float rstd = rsqrtf(var + 1e-5f);
    float v = z[(size_t)r * 128 + jj];
    float zn = fmaf((v - mean) * rstd, gamma[jj], beta[jj]);
    acc = fmaf(fmaxf(zn, 0.f), w2[jj], acc);
  }
  #pragma unroll
  for (int off = 32; off; off >>= 1) acc += __shfl_down(acc, off);
  if (lane == 0) out[r] = acc + b2[0];
}

extern "C" void kernel_launch(void* const* d_in, const int* in_sizes, int n_in,
                              void* d_out, int out_size, void* d_ws, size_t ws_size,
                              hipStream_t stream) {
  const float* x     = (const float*)d_in[0];
  const float* pos   = (const float*)d_in[1];
  const int*   eidx  = (const int*)d_in[2];
  const int*   batch = (const int*)d_in[3];
  const float* c1w1  = (const float*)d_in[4];
  const float* c1b1  = (const float*)d_in[5];
  const float* c1w2  = (const float*)d_in[6];
  const float* c1b2  = (const float*)d_in[7];
  const float* c2w1  = (const float*)d_in[8];
  const float* c2b1  = (const float*)d_in[9];
  const float* c2w2  = (const float*)d_in[10];
  const float* c2b2  = (const float*)d_in[11];
  const float* pw1   = (const float*)d_in[12];
  const float* gamma = (const float*)d_in[13];
  const float* beta  = (const float*)d_in[14];
  const float* pw2   = (const float*)d_in[15];
  const float* pb2   = (const float*)d_in[16];
  (void)n_in; (void)ws_size;

  const int N = in_sizes[0];
  const int E = in_sizes[2] / 2;
  const int G = out_size;
  const int* srcv = eidx;
  const int* dstv = eidx + E;

  char* w = (char*)d_ws;
  size_t o = 0;
  auto carve = [&](size_t bytes) { void* p = w + o; o = (o + bytes + 255) & ~(size_t)255; return p; };
  int Npad = ((N + 255) / 256) * 256;
  int* deg    = (int*)carve((size_t)Npad * 4);
  int* srcsP  = (int*)carve((size_t)N * DMAX * 4);
  float4* xp  = (float4*)carve((size_t)N * 16);
  uint*   hs1  = (uint*)carve((size_t)N * 64 * 4);    // conv1 out, bf16 packed
  uint*   pdb  = (uint*)carve((size_t)N * 64 * 4);    // conv2 pd bf16 packed
  uint*   psb  = (uint*)carve((size_t)N * 64 * 4);    // conv2 ps bf16 packed
  uint*   hs2  = (uint*)carve((size_t)N * 64 * 4);    // conv2 out bf16 packed
  ushort* w1t  = (ushort*)carve(16384 * 2);
  ushort* wdt  = (ushort*)carve(16384 * 2);
  ushort* wst  = (ushort*)carve(16384 * 2);
  ushort* w2t  = (ushort*)carve(16384 * 2);
  float* g    = (float*)carve((size_t)G * HID * 4);
  float* z    = (float*)carve((size_t)G * HID * 4);
  float* mv   = (float*)carve(256 * 4);

  // fused prep (zeros deg, g, mv in-kernel)
  k_prep<<<256, 256, 0, stream>>>(x, pos, c1w2, c2w1, c2w2,
                                  xp, deg, g, mv, w1t, wdt, wst, w2t, N, G, Npad);
  // XCD-sharded padded-CSR build
  int nwin = (E + ESHARD - 1) / ESHARD;
  k_build<<<nwin * 8, 256, 0, stream>>>(dstv, srcv, deg, srcsP, E);

  // conv1
  k_conv1<<<N, 64, 0, stream>>>(xp, deg, srcsP, c1w1, c1b1, hs1);
  // fused: h1 (LDS-resident) -> pd, ps  [64 rows/wave, weight-frag reuse]
  int gb128 = (N + 127) / 128;
  k_mfuse<<<gb128, 512, 0, stream>>>((const ushort*)hs1, w1t, wdt, wst, c1b2, c2b1, deg,
                                     psb, pdb, N);
  k_conv2<<<N, 64, 0, stream>>>(xp, deg, srcsP, pdb, psb, c2w1 + 256 * HID, hs2);
  // conv2 second linear + relu + fused pool
  int gb = (N + 63) / 64;
  k_mpool<<<gb, 256, 0, stream>>>((const ushort*)hs2, w2t, c2b2, deg, batch, g, N);
  // predictor (pgemm also accumulates BN raw sums into mv)
  k_pgemm<<<(G + 31) / 32, 256, 0, stream>>>(g, pw1, z, mv, G);
  k_final<<<(G + 3) / 4, 256, 0, stream>>>(z, mv, gamma, beta, pw2, pb2, (float*)d_out, G);
}